// Round 20
// baseline (849.475 us; speedup 1.0000x reference)
//
#include <hip/hip_runtime.h>
#include <hip/hip_bf16.h>
#include <stdint.h>

#define M_DIM 8192
#define K_DIM 4096
#define N_DIM 11008
#define NWORDS (N_DIM / 8)   // 1376
#define BM 128
#define BN 128
#define BK 64
#define NT (K_DIM / BK)      // 64
#define N_MAIN 10240         // main tiles cover N cols [0, 10240) = 40 x 256
#define NB_MAIN 1280         // 32 x 40 full 256x256 blocks
#define NB_TAIL 192          // 32 x 6 half 256x128 blocks (cols [10240, 11008))

typedef _Float16 half8 __attribute__((ext_vector_type(8)));  // 8 x f16 (4 VGPRs)
typedef __fp16 fp16x2 __attribute__((ext_vector_type(2)));
typedef __attribute__((ext_vector_type(4))) float f32x4;

typedef const __attribute__((address_space(1))) uint32_t glb_u32;
typedef __attribute__((address_space(3))) uint32_t lds_u32;

__device__ __forceinline__ uint32_t pkh(float lo, float hi) {
  union { fp16x2 h; uint32_t u; } cv;
  cv.h = __builtin_amdgcn_cvt_pkrtz(lo, hi);
  return cv.u;
}

__device__ __forceinline__ float ub(uint32_t v, int b) {
  return (float)((v >> (8 * b)) & 0xFFu);
}

// ---------------- fused pre-pass: blocks [0,16384) convert x; rest dequant W ----------------
#define XBLK 16384   // (M*K)/(256*8)
__global__ __launch_bounds__(256) void prep(const float* __restrict__ x,
                                            const int* __restrict__ qweight,
                                            const int* __restrict__ qzeros,
                                            const float* __restrict__ scales,
                                            __fp16* __restrict__ xh,
                                            __fp16* __restrict__ wt) {
  if (blockIdx.x < XBLK) {
    const size_t i8 = ((size_t)blockIdx.x * 256 + threadIdx.x) * 8;
    f32x4 v0 = *(const f32x4*)(x + i8);
    f32x4 v1 = *(const f32x4*)(x + i8 + 4);
    uint4 w;
    w.x = pkh(v0[0], v0[1]); w.y = pkh(v0[2], v0[3]);
    w.z = pkh(v1[0], v1[1]); w.w = pkh(v1[2], v1[3]);
    *(uint4*)(xh + i8) = w;
  } else {
    const int b2 = blockIdx.x - XBLK;
    const int c = b2 >> 4;                    // word column 0..1375 (8 n's)
    const int k = (b2 & 15) * 256 + threadIdx.x;
    const uint32_t q = (uint32_t)qweight[(size_t)k * NWORDS + c];
    const int g = k >> 7;                     // G=128
    const uint32_t z = (uint32_t)qzeros[(size_t)g * NWORDS + c];
    const float* sp = scales + (size_t)g * N_DIM + c * 8;
    const f32x4 s0 = *(const f32x4*)sp;
    const f32x4 s1 = *(const f32x4*)(sp + 4);
    #pragma unroll
    for (int j = 0; j < 8; ++j) {
      const int qv = (int)((q >> (4 * j)) & 15u);
      const int zv = (int)((z >> (4 * j)) & 15u);
      const float sj = (j < 4) ? s0[j & 3] : s1[j & 3];
      const float v = (float)(qv - zv) * sj;
      wt[(size_t)(c * 8 + j) * K_DIM + k] = (__fp16)v;   // coalesced over k (lane)
    }
  }
}

// ---------------- merged GEMM: 4 waves/block, wave tile 128x128 (DS-traffic-minimal) ----------------
// Per CU per K-tile: DS = 4 waves x 32 ds_read_b128 (1536cy) + DMA writes (512cy)
// = 2048cy < MFMA 2483cy -> matrix-bound (first config where that holds).
// VGPR: acc[8][8]=256 + b[8][2]=64 + pipeline ~40 => ~1 wave/SIMD; ILP replaces TLP.
// LDS dbuf 2x64KB; stage issues all 16 DMA at tile top -> full K-tile to land;
// vmcnt(0)+barrier per K-tile (RAW+WAR proven by alternating buffers).
__global__ __launch_bounds__(256, 1) void gemm_f16_256(
    const __fp16* __restrict__ xh,        // [M,K] fp16
    const __fp16* __restrict__ wt,        // [N,K] fp16
    float* __restrict__ out) {            // [M,N] fp32
  __shared__ uint4 lds4[8192];            // 128 KiB
  char* lds = (char*)lds4;

  const int t = threadIdx.x;
  const int lane = t & 63;
  const int wid = t >> 6;        // 0..3

  // shared read-side constants
  const int swr = (lane & 7) << 4;
  const int q16 = (lane >> 4) << 4;
  const int fr = lane & 15;
  const int sr = t >> 3;                              // 0..31: staging row within 32-row unit
  const int cb = (((t & 7) ^ (sr & 7)) << 4);         // inverse-swizzled source col
  const int ldst = wid * 1024;                        // wave-uniform; HW adds lane*16

  if (blockIdx.x < NB_MAIN) {
    // ============== MAIN: 256x256 tile, 4 waves, wave tile 128x128 ==============
    const int wm = wid >> 1;     // 0..1 (M half)
    const int wn = wid & 1;      // 0..1 (N half)

    // XCD swizzle: 1280 = 8 x 160
    const int flat = blockIdx.x;
    const int swz = (flat & 7) * 160 + (flat >> 3);
    const int bm0 = (swz & 31) * 256;
    const int bn0 = (swz >> 5) * 256;

    f32x4 acc[8][8];
    #pragma unroll
    for (int i = 0; i < 8; ++i)
      #pragma unroll
      for (int j = 0; j < 8; ++j)
        #pragma unroll
        for (int k = 0; k < 4; ++k) acc[i][j][k] = 0.0f;

    const char* gA = (const char*)xh + (size_t)(bm0 + sr) * (K_DIM * 2) + cb;
    const char* gB = (const char*)wt + (size_t)(bn0 + sr) * (K_DIM * 2) + cb;

    auto stage = [&](int kt) {           // 16 DMA/thread: A 32KB (8 units), B 32KB
      const int buf = (kt & 1) * 65536;
      const size_t ko = (size_t)kt * 128;
      #pragma unroll
      for (int u = 0; u < 8; ++u)
        __builtin_amdgcn_global_load_lds(
            (glb_u32*)(gA + (size_t)(u * 32) * (K_DIM * 2) + ko),
            (lds_u32*)(lds + buf + u * 4096 + ldst), 16, 0, 0);
      #pragma unroll
      for (int u = 0; u < 8; ++u)
        __builtin_amdgcn_global_load_lds(
            (glb_u32*)(gB + (size_t)(u * 32) * (K_DIM * 2) + ko),
            (lds_u32*)(lds + buf + 32768 + u * 4096 + ldst), 16, 0, 0);
    };

    stage(0);
    asm volatile("s_waitcnt vmcnt(0)" ::: "memory");
    __builtin_amdgcn_s_barrier();

    for (int kt = 0; kt < NT; ++kt) {
      const char* A = lds + (kt & 1) * 65536 + wm * 16384;          // 128 rows x 128B
      const char* B = lds + (kt & 1) * 65536 + 32768 + wn * 16384;  // 128 rows x 128B

      if (kt + 1 < NT) stage(kt + 1);    // 16 DMA in flight across the whole tile

      half8 b[8][2];
      #pragma unroll
      for (int ni = 0; ni < 8; ++ni)
        #pragma unroll
        for (int ks = 0; ks < 2; ++ks)
          b[ni][ks] = *(const half8*)(B + ((((ni * 16 + fr) << 7) + ks * 64 + q16) ^ swr));

      auto RD = [&](half8 (&d)[2], int mi) {
        #pragma unroll
        for (int ks = 0; ks < 2; ++ks)
          d[ks] = *(const half8*)(A + ((((mi * 16 + fr) << 7) + ks * 64 + q16) ^ swr));
      };
      auto MM = [&](int mi, half8 (&a)[2]) {   // 16-MFMA cluster
        __builtin_amdgcn_s_setprio(1);
        #pragma unroll
        for (int ni = 0; ni < 8; ++ni)
          #pragma unroll
          for (int ks = 0; ks < 2; ++ks)
            acc[mi][ni] = __builtin_amdgcn_mfma_f32_16x16x32_f16(
                a[ks], b[ni][ks], acc[mi][ni], 0, 0, 0);
        __builtin_amdgcn_s_setprio(0);
      };

      half8 aA[2], aB[2];                  // pipelined a-pairs (static roles)
      RD(aA, 0);
      RD(aB, 1); MM(0, aA);
      RD(aA, 2); MM(1, aB);
      RD(aB, 3); MM(2, aA);
      RD(aA, 4); MM(3, aB);
      RD(aB, 5); MM(4, aA);
      RD(aA, 6); MM(5, aB);
      RD(aB, 7); MM(6, aA);
      MM(7, aB);

      asm volatile("s_waitcnt vmcnt(0)" ::: "memory");
      __builtin_amdgcn_s_barrier();
    }

    // epilogue: C/D layout col = lane&15, row = 4*(lane>>4) + j
    #pragma unroll
    for (int mi = 0; mi < 8; ++mi) {
      #pragma unroll
      for (int ni = 0; ni < 8; ++ni) {
        const int grow = bm0 + wm * 128 + mi * 16 + ((lane >> 4) << 2);
        const int gcol = bn0 + wn * 128 + ni * 16 + (lane & 15);
        #pragma unroll
        for (int j = 0; j < 4; ++j)
          out[(size_t)(grow + j) * N_DIM + gcol] = acc[mi][ni][j];
      }
    }
  } else {
    // ============== TAIL: 256x128 tile, 4 waves, wave tile 128x64 ==============
    const int wm = wid >> 1;     // 0..1 (128-row half)
    const int wn = wid & 1;      // 0..1 (64-col half)

    // XCD swizzle: 192 = 8 x 24
    const int flat = blockIdx.x - NB_MAIN;
    const int swz = (flat & 7) * 24 + (flat >> 3);
    const int bm0 = (swz & 31) * 256;
    const int bn0 = N_MAIN + (swz >> 5) * 128;

    f32x4 acc[8][4];
    #pragma unroll
    for (int i = 0; i < 8; ++i)
      #pragma unroll
      for (int j = 0; j < 4; ++j)
        #pragma unroll
        for (int k = 0; k < 4; ++k) acc[i][j][k] = 0.0f;

    const char* gA = (const char*)xh + (size_t)(bm0 + sr) * (K_DIM * 2) + cb;
    const char* gB = (const char*)wt + (size_t)(bn0 + sr) * (K_DIM * 2) + cb;

    auto stage = [&](int kt) {           // 12 DMA: A 32KB (8 units), B 16KB (4)
      const int buf = (kt & 1) * 49152;
      const size_t ko = (size_t)kt * 128;
      #pragma unroll
      for (int u = 0; u < 8; ++u)
        __builtin_amdgcn_global_load_lds(
            (glb_u32*)(gA + (size_t)(u * 32) * (K_DIM * 2) + ko),
            (lds_u32*)(lds + buf + u * 4096 + ldst), 16, 0, 0);
      #pragma unroll
      for (int u = 0; u < 4; ++u)
        __builtin_amdgcn_global_load_lds(
            (glb_u32*)(gB + (size_t)(u * 32) * (K_DIM * 2) + ko),
            (lds_u32*)(lds + buf + 32768 + u * 4096 + ldst), 16, 0, 0);
    };

    stage(0);
    asm volatile("s_waitcnt vmcnt(0)" ::: "memory");
    __builtin_amdgcn_s_barrier();

    for (int kt = 0; kt < NT; ++kt) {
      const char* A = lds + (kt & 1) * 49152 + wm * 16384;          // 128 rows x 128B
      const char* B = lds + (kt & 1) * 49152 + 32768 + wn * 8192;   // 64 rows x 128B

      if (kt + 1 < NT) stage(kt + 1);

      half8 b[4][2];
      #pragma unroll
      for (int ni = 0; ni < 4; ++ni)
        #pragma unroll
        for (int ks = 0; ks < 2; ++ks)
          b[ni][ks] = *(const half8*)(B + ((((ni * 16 + fr) << 7) + ks * 64 + q16) ^ swr));

      auto RD = [&](half8 (&d)[2], int mi) {
        #pragma unroll
        for (int ks = 0; ks < 2; ++ks)
          d[ks] = *(const half8*)(A + ((((mi * 16 + fr) << 7) + ks * 64 + q16) ^ swr));
      };
      auto MM = [&](int mi, half8 (&a)[2]) {
        __builtin_amdgcn_s_setprio(1);
        #pragma unroll
        for (int ni = 0; ni < 4; ++ni)
          #pragma unroll
          for (int ks = 0; ks < 2; ++ks)
            acc[mi][ni] = __builtin_amdgcn_mfma_f32_16x16x32_f16(
                a[ks], b[ni][ks], acc[mi][ni], 0, 0, 0);
        __builtin_amdgcn_s_setprio(0);
      };

      half8 aA[2], aB[2];
      RD(aA, 0);
      RD(aB, 1); MM(0, aA);
      RD(aA, 2); MM(1, aB);
      RD(aB, 3); MM(2, aA);
      RD(aA, 4); MM(3, aB);
      RD(aB, 5); MM(4, aA);
      RD(aA, 6); MM(5, aB);
      RD(aB, 7); MM(6, aA);
      MM(7, aB);

      asm volatile("s_waitcnt vmcnt(0)" ::: "memory");
      __builtin_amdgcn_s_barrier();
    }

    #pragma unroll
    for (int mi = 0; mi < 8; ++mi) {
      #pragma unroll
      for (int ni = 0; ni < 4; ++ni) {
        const int grow = bm0 + wm * 128 + mi * 16 + ((lane >> 4) << 2);
        const int gcol = bn0 + wn * 64 + ni * 16 + (lane & 15);
        #pragma unroll
        for (int j = 0; j < 4; ++j)
          out[(size_t)(grow + j) * N_DIM + gcol] = acc[mi][ni][j];
      }
    }
  }
}

// ---------------- fallback: fused kernel (ws too small) ----------------
__global__ __launch_bounds__(256, 2) void wq_gemm(
    const float* __restrict__ x, const int* __restrict__ qweight,
    const int* __restrict__ qzeros, const float* __restrict__ scales,
    float* __restrict__ out) {
  __shared__ uint4 lds4[4096];
  char* lds = (char*)lds4;
  const int t = threadIdx.x;
  const int lane = t & 63;
  const int wid = t >> 6;
  const int bn0 = blockIdx.x * BN;
  const int bm0 = blockIdx.y * BM;
  const int c = t & 15;
  const int r0 = (t >> 4) << 2;
  const int wcol = (bn0 >> 3) + c;
  const int m_off = (wid >> 1) * 64;
  const int n_off = (wid & 1) * 64;
  f32x4 acc[4][4];
  #pragma unroll
  for (int i = 0; i < 4; ++i)
    #pragma unroll
    for (int j = 0; j < 4; ++j)
      #pragma unroll
      for (int k = 0; k < 4; ++k) acc[i][j][k] = 0.0f;
  uint32_t qw_r[4], zq_r;
  f32x4 sc_r[2];
  f32x4 a_rf[4][2];
  auto loadA = [&](int kt) {
    const float* gb = x + (size_t)(bm0 + (t >> 3)) * K_DIM + kt * BK + (t & 7) * 8;
    #pragma unroll
    for (int rr = 0; rr < 4; ++rr) {
      const float* p = gb + (size_t)rr * 32 * K_DIM;
      a_rf[rr][0] = *(const f32x4*)(p);
      a_rf[rr][1] = *(const f32x4*)(p + 4);
    }
  };
  auto writeA = [&](int buf) {
    char* Ab = lds + buf * 16384;
    const int swz = ((t >> 3) & 7) << 4;
    #pragma unroll
    for (int rr = 0; rr < 4; ++rr) {
      uint4 w;
      w.x = pkh(a_rf[rr][0][0], a_rf[rr][0][1]);
      w.y = pkh(a_rf[rr][0][2], a_rf[rr][0][3]);
      w.z = pkh(a_rf[rr][1][0], a_rf[rr][1][1]);
      w.w = pkh(a_rf[rr][1][2], a_rf[rr][1][3]);
      *(uint4*)(Ab + ((rr * 4096 + t * 16) ^ swz)) = w;
    }
  };
  auto issueB = [&](int kt) {
    const int kb = kt * BK + r0;
    const int* qp = qweight + (size_t)kb * NWORDS + wcol;
    qw_r[0] = (uint32_t)qp[0];
    qw_r[1] = (uint32_t)qp[NWORDS];
    qw_r[2] = (uint32_t)qp[2 * NWORDS];
    qw_r[3] = (uint32_t)qp[3 * NWORDS];
    const int g = kt >> 1;
    zq_r = (uint32_t)qzeros[(size_t)g * NWORDS + wcol];
    const float* sp = scales + (size_t)g * N_DIM + bn0 + c * 8;
    sc_r[0] = *(const f32x4*)sp;
    sc_r[1] = *(const f32x4*)(sp + 4);
  };
  auto dequantB = [&](int buf) {
    char* Bb = lds + 32768 + buf * 16384;
    const uint32_t ze = zq_r & 0x0F0F0F0Fu;
    const uint32_t zo = (zq_r >> 4) & 0x0F0F0F0Fu;
    uint32_t e[4], o[4];
    #pragma unroll
    for (int j = 0; j < 4; ++j) {
      e[j] = qw_r[j] & 0x0F0F0F0Fu;
      o[j] = (qw_r[j] >> 4) & 0x0F0F0F0Fu;
    }
    #pragma unroll
    for (int m = 0; m < 4; ++m) {
      const float sf0 = sc_r[(2 * m) >> 2][(2 * m) & 3];
      const float sf1 = sc_r[(2 * m + 1) >> 2][(2 * m + 1) & 3];
      const float cf0 = -ub(ze, m) * sf0;
      const float cf1 = -ub(zo, m) * sf1;
      {
        const float v0 = fmaf(ub(e[0], m), sf0, cf0);
        const float v1 = fmaf(ub(e[1], m), sf0, cf0);
        const float v2 = fmaf(ub(e[2], m), sf0, cf0);
        const float v3 = fmaf(ub(e[3], m), sf0, cf0);
        const int nl = c * 8 + 2 * m;
        int ad = (nl << 7) + (r0 << 1);
        ad ^= ((((nl >> 3) ^ nl) & 7) << 4);
        uint2 p; p.x = pkh(v0, v1); p.y = pkh(v2, v3);
        *(uint2*)(Bb + ad) = p;
      }
      {
        const float v0 = fmaf(ub(o[0], m), sf1, cf1);
        const float v1 = fmaf(ub(o[1], m), sf1, cf1);
        const float v2 = fmaf(ub(o[2], m), sf1, cf1);
        const float v3 = fmaf(ub(o[3], m), sf1, cf1);
        const int nl = c * 8 + 2 * m + 1;
        int ad = (nl << 7) + (r0 << 1);
        ad ^= ((((nl >> 3) ^ nl) & 7) << 4);
        uint2 p; p.x = pkh(v0, v1); p.y = pkh(v2, v3);
        *(uint2*)(Bb + ad) = p;
      }
    }
  };
  auto compute = [&](int buf) {
    const char* A = lds + buf * 16384;
    const char* B = lds + 32768 + buf * 16384;
    const int ra = m_off + (lane & 15);
    const int swa = (lane & 7) << 4;
    const int kb0 = (lane >> 4) << 4;
    #pragma unroll
    for (int ks = 0; ks < 2; ++ks) {
      half8 a[4], b[4];
      #pragma unroll
      for (int mi = 0; mi < 4; ++mi) {
        const int ad = ((ra + mi * 16) << 7) + ks * 64 + kb0;
        a[mi] = *(const half8*)(A + (ad ^ swa));
      }
      #pragma unroll
      for (int ni = 0; ni < 4; ++ni) {
        const int nl = n_off + ni * 16 + (lane & 15);
        int ad = (nl << 7) + ks * 64 + kb0;
        ad ^= ((((nl >> 3) ^ nl) & 7) << 4);
        b[ni] = *(const half8*)(B + ad);
      }
      #pragma unroll
      for (int mi = 0; mi < 4; ++mi)
        #pragma unroll
        for (int ni = 0; ni < 4; ++ni)
          acc[mi][ni] = __builtin_amdgcn_mfma_f32_16x16x32_f16(
              a[mi], b[ni], acc[mi][ni], 0, 0, 0);
    }
  };
  loadA(0); issueB(0); writeA(0); dequantB(0);
  __syncthreads();
  int cur = 0;
  for (int kt = 0; kt < NT; ++kt) {
    const int nxt = cur ^ 1;
    if (kt + 1 < NT) { loadA(kt + 1); issueB(kt + 1); }
    compute(cur);
    if (kt + 1 < NT) { writeA(nxt); dequantB(nxt); }
    __syncthreads();
    cur = nxt;
  }
  #pragma unroll
  for (int mi = 0; mi < 4; ++mi) {
    #pragma unroll
    for (int ni = 0; ni < 4; ++ni) {
      const int grow = bm0 + m_off + mi * 16 + ((lane >> 4) << 2);
      const int gcol = bn0 + n_off + ni * 16 + (lane & 15);
      #pragma unroll
      for (int j = 0; j < 4; ++j)
        out[(size_t)(grow + j) * N_DIM + gcol] = acc[mi][ni][j];
    }
  }
}

extern "C" void kernel_launch(void* const* d_in, const int* in_sizes, int n_in,
                              void* d_out, int out_size, void* d_ws, size_t ws_size,
                              hipStream_t stream) {
  const float* x = (const float*)d_in[0];
  const int* qw = (const int*)d_in[1];
  const int* qz = (const int*)d_in[2];
  const float* sc = (const float*)d_in[3];
  float* out = (float*)d_out;

  const size_t XH_BYTES = (size_t)M_DIM * K_DIM * 2;   // 67,108,864
  const size_t WT_BYTES = (size_t)N_DIM * K_DIM * 2;   // 90,177,536

  if (ws_size >= XH_BYTES + WT_BYTES) {
    __fp16* xh = (__fp16*)d_ws;
    __fp16* wt = (__fp16*)((char*)d_ws + XH_BYTES);
    prep<<<dim3(XBLK + NWORDS * 16), dim3(256), 0, stream>>>(x, qw, qz, sc, xh, wt);
    gemm_f16_256<<<dim3(NB_MAIN + NB_TAIL), dim3(256), 0, stream>>>(xh, wt, out);
  } else {
    wq_gemm<<<dim3(N_DIM / BN, M_DIM / BM), dim3(256), 0, stream>>>(x, qw, qz, sc, out);
  }
}